// Round 4
// baseline (165.335 us; speedup 1.0000x reference)
//
#include <hip/hip_runtime.h>

// Length regulator: out[b, p, :] = att_out[b, idx(b,p), :] for p < total[b], else 0.
// idx(b,p) = upper_bound(csum[b], p), csum = cumsum(round(duration*alpha)).
//
// B=32, L=256, D=512, MAX_LEN=2048. Output 128 MB fp32 -> pure write-stream.
//
// v5: FILL-SHAPED STRUCTURE. v0/v2/v4 all land at ~72us residual despite wildly
// different address-gen schedules -> the shared feature is shallow per-thread
// store streams (16 stores/thread, 2048 short-lived blocks). The 6.6 TB/s
// rocclr fill runs ~64+ stores/thread at ~10% occupancy. v5 copies that shape:
//   - 512 blocks (2/CU), POS=128 positions/block, 64 stores/thread
//   - chunked pipeline: 8 gather loads -> sched_barrier -> 8 nt stores,
//     8-deep store pipelining per wave, sustained for 8 chunks
//   - scan+search prologue amortized over 4x more output per block
//   - per-chunk zero fast path (mean total ~ MAX_LEN/2)
// Kept: shfl wave scan (2 barriers), hoisted idx_tab, XCD remap (lin%8=XCD,
// 4 whole batches per XCD -> gather reads L2-fit), nt stores, branchless search.

constexpr int B = 32;
constexpr int L = 256;
constexpr int D = 512;            // floats per row = 128 fvec4
constexpr int MAX_LEN = 2048;
constexpr int POS = 128;          // output positions per block
constexpr int THREADS = 256;      // 2 rows in flight (128 fvec4 lanes per row)
constexpr int CHUNK = 16;         // positions per chunk = 8 iters x 2 rows
constexpr int NCHUNK = POS / CHUNK;   // 8

typedef float fvec4 __attribute__((ext_vector_type(4)));

__global__ __launch_bounds__(THREADS) void length_regulator_kernel(
    const float* __restrict__ att_out,   // (B, L, D)
    const float* __restrict__ duration,  // (B, L)
    const int*   __restrict__ alpha_p,   // scalar
    float*       __restrict__ out)       // (B, MAX_LEN, D)
{
    __shared__ int csum[L];
    __shared__ int idx_tab[POS];
    __shared__ int wsum[4];

    const int tid  = threadIdx.x;
    const int lane = tid & 63;
    const int wave = tid >> 6;

    // XCD-aware remap: linear id round-robins over 8 XCDs; 512 % 8 == 0 ->
    // bijective. 16 consecutive slots = one batch; 4 whole batches per XCD.
    const int lin      = blockIdx.y * gridDim.x + blockIdx.x;   // 0..511
    const int xcd      = lin & 7;
    const int slot     = lin >> 3;                              // 0..63
    const int b        = xcd * (B / 8) + (slot >> 4);           // 4 batches/XCD
    const int pos_base = (slot & 15) * POS;

    const float alpha = (float)alpha_p[0];

    // ---- cumsum of r = round-half-even(duration*alpha): shfl scan, 2 barriers
    int x = (int)rintf(duration[b * L + tid] * alpha);
    #pragma unroll
    for (int off = 1; off < 64; off <<= 1) {
        int y = __shfl_up(x, off);
        x += (lane >= off) ? y : 0;
    }
    if (lane == 63) wsum[wave] = x;
    __syncthreads();
    const int w0 = wsum[0], w1 = wsum[1], w2 = wsum[2], w3 = wsum[3];
    const int total = w0 + w1 + w2 + w3;
    const int woff = (wave > 0 ? w0 : 0) + (wave > 1 ? w1 : 0) + (wave > 2 ? w2 : 0);
    csum[tid] = x + woff;
    __syncthreads();

    // ---- per-block idx table: 128 branchless searches, done ONCE ----
    if (tid < POS) {
        const int p = pos_base + tid;
        int lo = 0;                       // upper_bound = count of csum[] <= p
        #pragma unroll
        for (int step = 128; step >= 1; step >>= 1) {
            const int nxt = lo + step;
            if (nxt <= L && csum[nxt - 1] <= p) lo = nxt;
        }
        idx_tab[tid] = min(lo, L - 1);    // clamp (covers p >= total too)
    }
    __syncthreads();

    const int lane_r = tid & 127;
    const int rowsel = tid >> 7;          // 0 or 1

    const fvec4* __restrict__ src4 = (const fvec4*)(att_out + (size_t)b * L * D);
    fvec4* __restrict__ dst4 =
        (fvec4*)(out + ((size_t)b * MAX_LEN + pos_base) * D);

    const fvec4 z = (fvec4){0.f, 0.f, 0.f, 0.f};

    // ---- 8 chunks: {8 gather loads -> sched_barrier -> 8 nt stores} each ----
    #pragma unroll
    for (int c = 0; c < NCHUNK; ++c) {
        const int cbase = c * CHUNK;                   // wave-uniform

        if (pos_base + cbase >= total) {
            // pure zero chunk: no search reads, no loads, just stores
            #pragma unroll
            for (int j = 0; j < CHUNK / 2; ++j) {
                const int rp = cbase + 2 * j + rowsel;
                __builtin_nontemporal_store(
                    z, &dst4[(size_t)rp * (D / 4) + lane_r]);
            }
            continue;                                  // uniform branch
        }

        fvec4 v[CHUNK / 2];
        #pragma unroll
        for (int j = 0; j < CHUNK / 2; ++j) {
            const int srow = idx_tab[cbase + 2 * j + rowsel]; // broadcast read
            v[j] = src4[(size_t)srow * (D / 4) + lane_r];     // clamped
        }
        __builtin_amdgcn_sched_barrier(0);             // loads before stores

        if (pos_base + cbase + CHUNK <= total) {
            #pragma unroll
            for (int j = 0; j < CHUNK / 2; ++j) {
                const int rp = cbase + 2 * j + rowsel;
                __builtin_nontemporal_store(
                    v[j], &dst4[(size_t)rp * (D / 4) + lane_r]);
            }
        } else {
            #pragma unroll
            for (int j = 0; j < CHUNK / 2; ++j) {
                const int rp = cbase + 2 * j + rowsel;
                const bool keep = (pos_base + rp) < total;   // wave-uniform
                const fvec4 val = keep ? v[j] : z;
                __builtin_nontemporal_store(
                    val, &dst4[(size_t)rp * (D / 4) + lane_r]);
            }
        }
    }
}

extern "C" void kernel_launch(void* const* d_in, const int* in_sizes, int n_in,
                              void* d_out, int out_size, void* d_ws, size_t ws_size,
                              hipStream_t stream) {
    const float* att_out  = (const float*)d_in[0];
    const float* duration = (const float*)d_in[1];
    const int*   alpha    = (const int*)d_in[2];
    float*       out      = (float*)d_out;

    dim3 grid(MAX_LEN / POS, B);   // (16, 32) = 512 blocks = 2 per CU
    dim3 block(THREADS);
    length_regulator_kernel<<<grid, block, 0, stream>>>(att_out, duration, alpha, out);
}

// Round 5
// 160.273 us; speedup vs baseline: 1.0316x; 1.0316x over previous
//
#include <hip/hip_runtime.h>

// Length regulator: out[b, p, :] = att_out[b, idx(b,p), :] for p < total[b], else 0.
// idx(b,p) = upper_bound(csum[b], p), csum = cumsum(round(duration*alpha)).
//
// B=32, L=256, D=512, MAX_LEN=2048. Output 128 MB fp32 -> pure write-stream.
//
// v6: TWO-KERNEL SPLIT (decisive test of the prologue-cost hypothesis).
//  - Running tally (residual over the in-graph 512MiB poison fill):
//      v0 (per-pass search)        ~73.7us
//      v2 (hoisted idx, 2048 blk)  ~70.5us   <- best
//      v4 (two-phase + nt)         ~73us
//      v5 (512 blk, deep streams)  ~81us     <- deep-stream theory refuted
//    Copy-loop BODY variations are exhausted (<=5% effect). Remaining lever:
//    every block pays {cold duration load -> shfl scan -> 3 barriers -> search}
//    before its first store. v6 hoists ALL of that into a tiny kernel 1
//    (32 blocks, ~2us) writing idx tables + totals to d_ws; kernel 2 is v2's
//    exact best-measured copy loop with a 1-barrier, 2-load prologue.
//  - If this is neutral (~150-160 tracking fill clock), the harness-floor
//    hypothesis is confirmed by exhaustion -> declare roofline next round.

constexpr int B = 32;
constexpr int L = 256;
constexpr int D = 512;            // floats per row = 128 fvec4
constexpr int MAX_LEN = 2048;
constexpr int POS = 32;           // output positions per copy-block
constexpr int THREADS = 256;

typedef float fvec4 __attribute__((ext_vector_type(4)));

// ---- kernel 1: per-batch cumsum + full idx table -> workspace ----
__global__ __launch_bounds__(THREADS) void idx_precompute_kernel(
    const float* __restrict__ duration,  // (B, L)
    const int*   __restrict__ alpha_p,   // scalar
    int*         __restrict__ ws_idx,    // (B, MAX_LEN)
    int*         __restrict__ ws_total)  // (B)
{
    __shared__ int csum[L];
    __shared__ int wsum[4];

    const int b    = blockIdx.x;
    const int tid  = threadIdx.x;
    const int lane = tid & 63;
    const int wave = tid >> 6;

    const float alpha = (float)alpha_p[0];

    int x = (int)rintf(duration[b * L + tid] * alpha);
    #pragma unroll
    for (int off = 1; off < 64; off <<= 1) {
        int y = __shfl_up(x, off);
        x += (lane >= off) ? y : 0;
    }
    if (lane == 63) wsum[wave] = x;
    __syncthreads();
    const int w0 = wsum[0], w1 = wsum[1], w2 = wsum[2], w3 = wsum[3];
    const int woff = (wave > 0 ? w0 : 0) + (wave > 1 ? w1 : 0) + (wave > 2 ? w2 : 0);
    csum[tid] = x + woff;
    __syncthreads();
    if (tid == 0) ws_total[b] = w0 + w1 + w2 + w3;

    // 8 branchless searches per thread -> full (b, 2048) idx table
    #pragma unroll
    for (int k = 0; k < MAX_LEN / THREADS; ++k) {
        const int p = k * THREADS + tid;
        int lo = 0;                       // upper_bound = count of csum[] <= p
        #pragma unroll
        for (int step = 128; step >= 1; step >>= 1) {
            const int nxt = lo + step;
            if (nxt <= L && csum[nxt - 1] <= p) lo = nxt;
        }
        ws_idx[b * MAX_LEN + p] = min(lo, L - 1);   // clamp covers p >= total
    }
}

// ---- kernel 2: v2's copy loop, prologue reduced to 2 loads + 1 barrier ----
__global__ __launch_bounds__(THREADS) void length_regulator_copy_kernel(
    const float* __restrict__ att_out,   // (B, L, D)
    const int*   __restrict__ ws_idx,    // (B, MAX_LEN)
    const int*   __restrict__ ws_total,  // (B)
    float*       __restrict__ out)       // (B, MAX_LEN, D)
{
    __shared__ int s_idx[POS];

    const int tid = threadIdx.x;

    // XCD-aware remap (unchanged from v2): lin%8 = XCD, 4 whole batches/XCD.
    const int lin      = blockIdx.y * gridDim.x + blockIdx.x;   // 0..2047
    const int xcd      = lin & 7;
    const int slot     = lin >> 3;                              // 0..255
    const int b        = xcd * (B / 8) + (slot >> 6);
    const int pos_base = (slot & 63) * POS;

    const int total = ws_total[b];       // block-uniform scalar load

    const int lane_r = tid & 127;
    const int rowsel = tid >> 7;          // 0 or 1

    fvec4* __restrict__ dst4 =
        (fvec4*)(out + ((size_t)b * MAX_LEN + pos_base) * D);

    // all-zero fast path (block-uniform): no table read, no barrier, no loads
    if (pos_base >= total) {
        const fvec4 z = (fvec4){0.f, 0.f, 0.f, 0.f};
        #pragma unroll
        for (int i = 0; i < POS; i += 2)
            dst4[(size_t)(i + rowsel) * (D / 4) + lane_r] = z;
        return;
    }

    if (tid < POS) s_idx[tid] = ws_idx[b * MAX_LEN + pos_base + tid];
    __syncthreads();

    const fvec4* __restrict__ src4 = (const fvec4*)(att_out + (size_t)b * L * D);

    #pragma unroll
    for (int i = 0; i < POS; i += 2) {
        const int rp   = i + rowsel;
        const int srow = s_idx[rp];                        // broadcast LDS read
        fvec4 t = src4[(size_t)srow * (D / 4) + lane_r];   // clamped, in-bounds
        const bool keep = (pos_base + rp) < total;         // wave-uniform
        const fvec4 val = keep ? t : (fvec4){0.f, 0.f, 0.f, 0.f};
        dst4[(size_t)rp * (D / 4) + lane_r] = val;
    }
}

extern "C" void kernel_launch(void* const* d_in, const int* in_sizes, int n_in,
                              void* d_out, int out_size, void* d_ws, size_t ws_size,
                              hipStream_t stream) {
    const float* att_out  = (const float*)d_in[0];
    const float* duration = (const float*)d_in[1];
    const int*   alpha    = (const int*)d_in[2];
    float*       out      = (float*)d_out;

    int* ws_idx   = (int*)d_ws;              // 256 KB
    int* ws_total = ws_idx + B * MAX_LEN;    // + 128 B

    idx_precompute_kernel<<<dim3(B), dim3(THREADS), 0, stream>>>(
        duration, alpha, ws_idx, ws_total);

    dim3 grid(MAX_LEN / POS, B);   // (64, 32) = 2048 blocks
    length_regulator_copy_kernel<<<grid, dim3(THREADS), 0, stream>>>(
        att_out, ws_idx, ws_total, out);
}

// Round 6
// 151.168 us; speedup vs baseline: 1.0937x; 1.0602x over previous
//
#include <hip/hip_runtime.h>

// Length regulator: out[b, p, :] = att_out[b, idx(b,p), :] for p < total[b], else 0.
// idx(b,p) = upper_bound(csum[b], p), csum = cumsum(round(duration*alpha)).
//
// B=32, L=256, D=512, MAX_LEN=2048. Output 128 MB fp32 -> pure write-stream.
//
// FINAL (v7 = v2 verbatim, the best-measured variant at 150.9us).
// Exhaustion evidence that this is the floor (all fill-clock-normalized):
//   v0 per-pass dependent search          ~73.7us residual
//   v2 hoisted idx_tab, 2048 blocks       ~70.5us  <- BEST
//   v4 two-phase + nontemporal stores     ~73us
//   v5 512 blocks, 64 stores/thread       ~81us    (deep-stream theory refuted)
//   v6 split precompute kernel            ~79us    (prologue theory refuted)
// The timed harness region is dominated by a 512 MiB re-poison fill
// (~81us @ 6.5 TB/s, visible as every top-5 rocprof dispatch); this kernel's
// own roofline is ~23us (128 MiB writes + ~17 MiB reads @ 6.5 TB/s) and it
// never appears in the top-5. Kernel-side variation is exhausted at <=5%.

constexpr int B = 32;
constexpr int L = 256;
constexpr int D = 512;            // floats per row = 128 float4
constexpr int MAX_LEN = 2048;
constexpr int POS = 32;           // output positions per block
constexpr int THREADS = 256;      // 2 rows in flight (128 float4 lanes per row)

__global__ __launch_bounds__(THREADS) void length_regulator_kernel(
    const float* __restrict__ att_out,   // (B, L, D)
    const float* __restrict__ duration,  // (B, L)
    const int*   __restrict__ alpha_p,   // scalar
    float*       __restrict__ out)       // (B, MAX_LEN, D)
{
    __shared__ int csum[L];
    __shared__ int idx_tab[POS];
    __shared__ int wsum[4];

    const int tid  = threadIdx.x;
    const int lane = tid & 63;
    const int wave = tid >> 6;

    // XCD-aware remap: linear block id round-robins over 8 XCDs (measured
    // mapping). 4 whole batches per XCD -> gather reads L2-fit (2MB < 4MB).
    const int lin      = blockIdx.y * gridDim.x + blockIdx.x;   // 0..2047
    const int xcd      = lin & 7;
    const int slot     = lin >> 3;                              // 0..255
    const int b        = xcd * (B / 8) + (slot >> 6);           // 4 batches/XCD
    const int pos_base = (slot & 63) * POS;

    const float alpha = (float)alpha_p[0];

    // ---- cumsum of r = round-half-even(duration*alpha): shfl scan, 2 barriers
    int x = (int)rintf(duration[b * L + tid] * alpha);
    #pragma unroll
    for (int off = 1; off < 64; off <<= 1) {
        int y = __shfl_up(x, off);
        x += (lane >= off) ? y : 0;
    }
    if (lane == 63) wsum[wave] = x;
    __syncthreads();
    const int w0 = wsum[0], w1 = wsum[1], w2 = wsum[2], w3 = wsum[3];
    const int total = w0 + w1 + w2 + w3;
    const int woff = (wave > 0 ? w0 : 0) + (wave > 1 ? w1 : 0) + (wave > 2 ? w2 : 0);
    csum[tid] = x + woff;
    __syncthreads();

    // ---- per-block idx table: 32 branchless searches, done ONCE ----
    if (tid < POS) {
        const int p = pos_base + tid;
        int lo = 0;                       // upper_bound = count of csum[] <= p
        #pragma unroll
        for (int step = 128; step >= 1; step >>= 1) {
            const int nxt = lo + step;
            if (nxt <= L && csum[nxt - 1] <= p) lo = nxt;
        }
        idx_tab[tid] = min(lo, L - 1);    // clamp (covers p >= total too)
    }
    __syncthreads();

    // ---- copy: 16 independent passes x 2 rows x 128 lanes x float4 ----
    const int lane_r = tid & 127;
    const int rowsel = tid >> 7;          // 0 or 1

    const float4* __restrict__ src4 = (const float4*)(att_out + (size_t)b * L * D);
    float4*       __restrict__ dst4 =
        (float4*)(out + ((size_t)b * MAX_LEN + pos_base) * D);

    #pragma unroll
    for (int i = 0; i < POS; i += 2) {
        const int rp = i + rowsel;                    // row within block
        const int p  = pos_base + rp;
        const int srow = idx_tab[rp];                 // broadcast LDS read
        float4 t = src4[(size_t)srow * (D / 4) + lane_r];   // clamped, in-bounds
        float4 val;
        const bool keep = (p < total);                // wave-uniform
        val.x = keep ? t.x : 0.f;
        val.y = keep ? t.y : 0.f;
        val.z = keep ? t.z : 0.f;
        val.w = keep ? t.w : 0.f;
        dst4[(size_t)rp * (D / 4) + lane_r] = val;
    }
}

extern "C" void kernel_launch(void* const* d_in, const int* in_sizes, int n_in,
                              void* d_out, int out_size, void* d_ws, size_t ws_size,
                              hipStream_t stream) {
    const float* att_out  = (const float*)d_in[0];
    const float* duration = (const float*)d_in[1];
    const int*   alpha    = (const int*)d_in[2];
    float*       out      = (float*)d_out;

    dim3 grid(MAX_LEN / POS, B);   // (64, 32) = 2048 blocks = 256 CUs x 8 resident
    dim3 block(THREADS);
    length_regulator_kernel<<<grid, block, 0, stream>>>(att_out, duration, alpha, out);
}